// Round 1
// baseline (39.573 us; speedup 1.0000x reference)
//
#include <hip/hip_runtime.h>
#include <float.h>
#include <limits.h>
#include <math.h>

// Problem constants (fixed shapes from setup_inputs)
constexpr int kB = 24;
constexpr int kC = 4;
constexpr int kHW = 65536;       // 256*256
constexpr int kD = 64;
constexpr int kNChunk = 32;
constexpr int kChunk = kHW / kNChunk;   // 2048 pixels per chunk
constexpr int kMaxS = 8;                // supports sample_num <= 8 (actual 5)
constexpr float kTau = 0.07f;
constexpr float kEpsLog = 1e-6f;
constexpr float kEpsDen = 1e-8f;
constexpr float kEpsNorm = 1e-12f;

__device__ __forceinline__ bool beats(float v1, int i1, float v2, int i2) {
    // descending by value; ties -> smaller index wins (matches jax.lax.top_k)
    return (v1 > v2) || (v1 == v2 && i1 < i2);
}

__device__ __forceinline__ float wave_sum(float x) {
    #pragma unroll
    for (int o = 32; o > 0; o >>= 1) x += __shfl_xor(x, o, 64);
    return x;
}

// ---------------------------------------------------------------------------
// K1: per (batch, chunk) top-S of unc[j] = sum_c pred*log(pred+eps)
// grid: kB*kNChunk blocks, 256 threads
// ---------------------------------------------------------------------------
__global__ __launch_bounds__(256) void k_topk_partial(
        const float* __restrict__ pred, const int* __restrict__ snum,
        float* __restrict__ cand_val, int* __restrict__ cand_idx) {
    int S = snum[0];
    S = S < 1 ? 1 : (S > kMaxS ? kMaxS : S);
    const int t = threadIdx.x;
    const int b = blockIdx.x / kNChunk;
    const int chunk = blockIdx.x % kNChunk;
    const int base = chunk * kChunk;
    const int j0 = base + t * 8;   // 8 consecutive pixels per thread
    const float* pb = pred + (size_t)b * kC * kHW + j0;

    float u[8];
    #pragma unroll
    for (int i = 0; i < 8; ++i) u[i] = 0.f;
    #pragma unroll
    for (int c = 0; c < kC; ++c) {
        float4 a = *reinterpret_cast<const float4*>(pb + (size_t)c * kHW);
        float4 d = *reinterpret_cast<const float4*>(pb + (size_t)c * kHW + 4);
        u[0] += a.x * __logf(a.x + kEpsLog);
        u[1] += a.y * __logf(a.y + kEpsLog);
        u[2] += a.z * __logf(a.z + kEpsLog);
        u[3] += a.w * __logf(a.w + kEpsLog);
        u[4] += d.x * __logf(d.x + kEpsLog);
        u[5] += d.y * __logf(d.y + kEpsLog);
        u[6] += d.z * __logf(d.z + kEpsLog);
        u[7] += d.w * __logf(d.w + kEpsLog);
    }

    // per-thread sorted top-S (static indexing only -> stays in registers)
    float lv[kMaxS]; int li[kMaxS];
    #pragma unroll
    for (int k = 0; k < kMaxS; ++k) { lv[k] = -FLT_MAX; li[k] = INT_MAX; }
    #pragma unroll
    for (int i = 0; i < 8; ++i) {
        float v = u[i]; int j = j0 + i;
        #pragma unroll
        for (int k = 0; k < kMaxS; ++k) {
            if (k < S && beats(v, j, lv[k], li[k])) {
                float tv = lv[k]; int ti = li[k];
                lv[k] = v; li[k] = j;
                v = tv; j = ti;
            }
        }
    }

    // block-level S rounds of argmax over 256 thread-heads
    __shared__ float sv[256];
    __shared__ int   si[256];
    for (int r = 0; r < S; ++r) {
        float hv = -FLT_MAX; int hi = INT_MAX;
        #pragma unroll
        for (int k = 0; k < kMaxS; ++k)
            if (beats(lv[k], li[k], hv, hi)) { hv = lv[k]; hi = li[k]; }
        sv[t] = hv; si[t] = hi;
        __syncthreads();
        for (int s = 128; s > 0; s >>= 1) {
            if (t < s && beats(sv[t + s], si[t + s], sv[t], si[t])) {
                sv[t] = sv[t + s]; si[t] = si[t + s];
            }
            __syncthreads();
        }
        const float wv = sv[0];
        const int wi = si[0];
        __syncthreads();
        if (t == 0) {
            cand_val[(size_t)blockIdx.x * kMaxS + r] = wv;
            cand_idx[(size_t)blockIdx.x * kMaxS + r] = wi;
        }
        // remove winner from my local list (pixel indices are unique)
        #pragma unroll
        for (int k = 0; k < kMaxS; ++k)
            if (li[k] == wi) { lv[k] = -FLT_MAX; li[k] = INT_MAX; }
    }
}

// ---------------------------------------------------------------------------
// K2: per batch — merge chunk candidates to global top-S, then wave 0
// gathers the 3 views' vectors at the top pixels and computes the loss.
// grid: kB blocks, 256 threads
// ---------------------------------------------------------------------------
__global__ __launch_bounds__(256) void k_merge_loss(
        const float* __restrict__ proj, const int* __restrict__ idxp,
        const int* __restrict__ snum,
        const float* __restrict__ cand_val, const int* __restrict__ cand_idx,
        float* __restrict__ per_b) {
    int S = snum[0];
    S = S < 1 ? 1 : (S > kMaxS ? kMaxS : S);
    const int b = blockIdx.x;
    const int t = threadIdx.x;

    __shared__ float sv[256];
    __shared__ int   si[256];
    __shared__ int   topPix[kMaxS];

    // load my candidate (chunk-major ordering)
    float rv = -FLT_MAX; int ri = INT_MAX;
    const int ncand = kNChunk * S;   // <= 256
    if (t < ncand) {
        const int chunk = t / S, r = t % S;
        rv = cand_val[(size_t)(b * kNChunk + chunk) * kMaxS + r];
        ri = cand_idx[(size_t)(b * kNChunk + chunk) * kMaxS + r];
    }
    for (int r = 0; r < S; ++r) {
        sv[t] = rv; si[t] = ri;
        __syncthreads();
        for (int s = 128; s > 0; s >>= 1) {
            if (t < s && beats(sv[t + s], si[t + s], sv[t], si[t])) {
                sv[t] = sv[t + s]; si[t] = si[t + s];
            }
            __syncthreads();
        }
        const int wi = si[0];
        __syncthreads();            // everyone captured wi before sv reuse
        if (t == 0) topPix[r] = wi;
        if (ri == wi) { rv = -FLT_MAX; ri = INT_MAX; }
    }
    __syncthreads();

    // ---- phase 2: loss on wave 0 (lanes = feature dim d) ----
    if (t < kD) {
        const int lane = t;
        int idx0 = idxp[0];
        idx0 = idx0 < 0 ? 0 : (idx0 > 2 ? 2 : idx0);
        const int v1 = (idx0 == 0) ? 1 : 0;
        const int v2 = (idx0 == 2) ? 1 : 2;

        float cv[kMaxS], a1[kMaxS], a2[kMaxS];
        #pragma unroll
        for (int s = 0; s < kMaxS; ++s) {
            cv[s] = 0.f; a1[s] = 0.f; a2[s] = 0.f;
            if (s < S) {
                const int pix = topPix[s];
                const size_t off = (size_t)lane * kHW + pix;
                cv[s] = proj[((size_t)(idx0 * kB + b) * kD) * kHW + off];
                a1[s] = proj[((size_t)(v1 * kB + b) * kD) * kHW + off];
                a2[s] = proj[((size_t)(v2 * kB + b) * kD) * kHW + off];
            }
        }
        // L2-normalize each vector (matches p / max(norm, 1e-12))
        #pragma unroll
        for (int s = 0; s < kMaxS; ++s) {
            if (s < S) {
                cv[s] = cv[s] / fmaxf(sqrtf(wave_sum(cv[s] * cv[s])), kEpsNorm);
                a1[s] = a1[s] / fmaxf(sqrtf(wave_sum(a1[s] * a1[s])), kEpsNorm);
                a2[s] = a2[s] / fmaxf(sqrtf(wave_sum(a2[s] * a2[s])), kEpsNorm);
            }
        }
        // positive term: exp((c.p1 + c.p2)/tau)
        float pl[kMaxS];
        #pragma unroll
        for (int s = 0; s < kMaxS; ++s) {
            pl[s] = 0.f;
            if (s < S) {
                const float ps = wave_sum(cv[s] * a1[s]) + wave_sum(cv[s] * a2[s]);
                pl[s] = expf(ps / kTau);
            }
        }
        // negatives: column sums of exp(c_i.c_j/tau) minus diagonal
        float neg[kMaxS];
        #pragma unroll
        for (int s = 0; s < kMaxS; ++s) neg[s] = 0.f;
        #pragma unroll
        for (int i = 0; i < kMaxS; ++i) {
            if (i < S) {
                #pragma unroll
                for (int j = 0; j < kMaxS; ++j) {
                    if (j < S) {
                        const float dij = wave_sum(cv[i] * cv[j]);
                        if (i != j) neg[j] += expf(dij / kTau);
                    }
                }
            }
        }
        float acc = 0.f;
        #pragma unroll
        for (int s = 0; s < kMaxS; ++s)
            if (s < S) acc += -logf(pl[s] / (pl[s] + neg[s] + kEpsDen));
        if (lane == 0) per_b[b] = acc / (float)S;
    }
}

// ---------------------------------------------------------------------------
// K3: deterministic serial final reduction (fixed fp order, no atomics)
// ---------------------------------------------------------------------------
__global__ void k_finalize(const float* __restrict__ per_b, float* __restrict__ out) {
    if (threadIdx.x == 0 && blockIdx.x == 0) {
        float s = 0.f;
        for (int b = 0; b < kB; ++b) s += per_b[b];
        out[0] = s / (float)kB;
    }
}

extern "C" void kernel_launch(void* const* d_in, const int* in_sizes, int n_in,
                              void* d_out, int out_size, void* d_ws, size_t ws_size,
                              hipStream_t stream) {
    const float* pred = (const float*)d_in[0];
    const float* proj = (const float*)d_in[1];
    // d_in[2] mask, d_in[3] pseudo_label: unused by the reference
    const int* idxp  = (const int*)d_in[4];
    const int* snump = (const int*)d_in[5];
    float* out = (float*)d_out;

    char* ws = (char*)d_ws;
    float* cand_val = (float*)ws;                                 // kB*kNChunk*kMaxS
    int*   cand_idx = (int*)(cand_val + kB * kNChunk * kMaxS);    // kB*kNChunk*kMaxS
    float* per_b    = (float*)(cand_idx + kB * kNChunk * kMaxS);  // kB

    k_topk_partial<<<kB * kNChunk, 256, 0, stream>>>(pred, snump, cand_val, cand_idx);
    k_merge_loss<<<kB, 256, 0, stream>>>(proj, idxp, snump, cand_val, cand_idx, per_b);
    k_finalize<<<1, 64, 0, stream>>>(per_b, out);
}